// Round 3
// baseline (245.244 us; speedup 1.0000x reference)
//
#include <hip/hip_runtime.h>

#define N_PP   8192
#define N_A    8192
#define DIM    16
#define NEDGE  262144
#define TPB    256

// Block partition of the single fused kernel (all counts exactly aligned so
// every block targets exactly one ws slot):
//   [0, 2048)      pp matrix units   (4 waves/block x 8192 units of 32row x 256col)
//   [2048, 4096)   ap matrix units
//   [4096, 5120)   pp edges          (256 edges/block)
//   [5120, 6144)   ap edges
#define NB_MAT_PP  2048
#define NB_MAT_AP  2048
#define NB_EDGE_PP 1024
#define NB_EDGE_AP 1024
#define NB_TOTAL   (NB_MAT_PP + NB_MAT_AP + NB_EDGE_PP + NB_EDGE_AP)

// ws layout (floats): [0]=nonlink_pp [1]=link_pp [2]=nonlink_ap [3]=link_ap
// [4] = completion counter (as uint)

typedef short bf16x8 __attribute__((ext_vector_type(8)));
typedef float f32x4  __attribute__((ext_vector_type(4)));
typedef unsigned u32x4 __attribute__((ext_vector_type(4)));

__global__ void zero_ws_kernel(float* __restrict__ ws) {
    if (threadIdx.x < 8) ws[threadIdx.x] = 0.0f;
}

__device__ __forceinline__ float waveReduce(float v) {
#pragma unroll
    for (int off = 32; off > 0; off >>= 1)
        v += __shfl_down(v, off, 64);
    return v;
}

// fp32 -> bf16 with round-to-nearest-even, pure bit ops (trivially copyable).
__device__ __forceinline__ unsigned bf16_rne(float f) {
    unsigned u = __builtin_bit_cast(unsigned, f);
    return (u + 0x7FFFu + ((u >> 16) & 1u)) >> 16;
}
__device__ __forceinline__ unsigned packbf2(float a, float b) {
    return bf16_rne(a) | (bf16_rne(b) << 16);
}

// One wave computes sum over a 32-row x 256-col tile of exp(br+bc - dist).
// Rows from X (p_star), cols from Y (p or a). MFMA 16x16x32 bf16, K padded:
//   A[m=lane&15][k=quad*8+j], B[k=quad*8+j][n=lane&15], quads 2,3 hold zeros.
//   D: col=lane&15, row=quad*4+reg  (HW-verified layouts, m89/m91)
__device__ __forceinline__ float matrix_unit(
    const float* __restrict__ X, const float* __restrict__ Y,
    const float* __restrict__ rB, const float* __restrict__ cB,
    int i0, int c0, bool isPP)
{
    const int lane = threadIdx.x & 63;
    const int quad = lane >> 4;
    const int l16  = lane & 15;
    const f32x4 zero4 = {0.f, 0.f, 0.f, 0.f};

    bf16x8 afrag[2];
    float  x2r[2][4], br[2][4];
#pragma unroll
    for (int s = 0; s < 2; ++s) {
        float part = 0.f;
        bf16x8 af = {};
        if (quad < 2) {
            const float4* rp = (const float4*)(X + (i0 + s * 16 + l16) * DIM);
            float4 f0 = rp[quad * 2], f1 = rp[quad * 2 + 1];
            u32x4 uv = { packbf2(f0.x, f0.y), packbf2(f0.z, f0.w),
                         packbf2(f1.x, f1.y), packbf2(f1.z, f1.w) };
            af = __builtin_bit_cast(bf16x8, uv);
            part = f0.x*f0.x + f0.y*f0.y + f0.z*f0.z + f0.w*f0.w
                 + f1.x*f1.x + f1.y*f1.y + f1.z*f1.z + f1.w*f1.w;
        }
        afrag[s] = af;
        float full = part + __shfl_xor(part, 16, 64);   // rows' |x|^2 at lanes 0..15
        float bl   = rB[i0 + s * 16 + l16];             // rows' bias at lanes 0..15
#pragma unroll
        for (int r = 0; r < 4; ++r) {
            x2r[s][r] = __shfl(full, quad * 4 + r, 64);
            br[s][r]  = __shfl(bl,   quad * 4 + r, 64);
        }
    }

    float acc = 0.f;
    for (int t = 0; t < 16; ++t) {
        const int jt = c0 + t * 16;
        float part = 0.f;
        bf16x8 bfrag = {};
        if (quad < 2) {
            const float4* rp = (const float4*)(Y + (jt + l16) * DIM);
            float4 g0 = rp[quad * 2], g1 = rp[quad * 2 + 1];
            u32x4 uv = { packbf2(g0.x, g0.y), packbf2(g0.z, g0.w),
                         packbf2(g1.x, g1.y), packbf2(g1.z, g1.w) };
            bfrag = __builtin_bit_cast(bf16x8, uv);
            part = g0.x*g0.x + g0.y*g0.y + g0.z*g0.z + g0.w*g0.w
                 + g1.x*g1.x + g1.y*g1.y + g1.z*g1.z + g1.w*g1.w;
        }
        float full = part + __shfl_xor(part, 16, 64);
        float y2c  = __shfl(full, l16, 64);
        float bc   = cB[jt + l16];

        f32x4 d0 = __builtin_amdgcn_mfma_f32_16x16x32_bf16(afrag[0], bfrag, zero4, 0, 0, 0);
        f32x4 d1 = __builtin_amdgcn_mfma_f32_16x16x32_bf16(afrag[1], bfrag, zero4, 0, 0, 0);

#pragma unroll
        for (int s = 0; s < 2; ++s) {
            const int rbase = i0 + s * 16;
            if (isPP && (jt + 15 <= rbase)) continue;       // whole strip has col<=row
            f32x4 d = s ? d1 : d0;
            float term[4];
#pragma unroll
            for (int r = 0; r < 4; ++r) {
                float d2 = fmaf(-2.f, d[r], x2r[s][r] + y2c);
                d2 = fmaxf(d2, 0.f);
                float arg = (br[s][r] + bc) - __builtin_amdgcn_sqrtf(d2);
                term[r] = __expf(arg);
            }
            if (isPP && (jt < rbase + 16)) {                // diagonal-straddling tile
#pragma unroll
                for (int r = 0; r < 4; ++r)
                    if ((jt + l16) <= (rbase + quad * 4 + r)) term[r] = 0.f;
            }
#pragma unroll
            for (int r = 0; r < 4; ++r) acc += term[r];
        }
    }
    return acc;
}

__global__ __launch_bounds__(TPB) void main_kernel(
    const float* __restrict__ p_star, const float* __restrict__ p,
    const float* __restrict__ a, const float* __restrict__ beta_ap,
    const float* __restrict__ gamma_pp, const int* __restrict__ edges_pp,
    const int* __restrict__ edges_ap, float* __restrict__ ws,
    float* __restrict__ out)
{
    __shared__ float smred[4];
    const int b   = blockIdx.x;
    const int tid = threadIdx.x;
    const int wid = tid >> 6;

    float val = 0.f;
    int slot;

    if (b < NB_MAT_PP + NB_MAT_AP) {
        const bool isPP = (b < NB_MAT_PP);
        const int u  = (isPP ? b : b - NB_MAT_PP) * 4 + wid;   // 0..8191
        const int i0 = (u >> 5) * 32;
        const int c0 = (u & 31) * 256;
        slot = isPP ? 0 : 2;
        if (!(isPP && (c0 + 255 <= i0))) {
            val = matrix_unit(p_star, isPP ? p : a,
                              isPP ? gamma_pp : beta_ap,
                              (isPP ? gamma_pp : beta_ap) + N_PP,
                              i0, c0, isPP);
        }
    } else {
        const int  eb   = b - (NB_MAT_PP + NB_MAT_AP);
        const bool isPP = (eb < NB_EDGE_PP);
        const int  e    = (isPP ? eb : eb - NB_EDGE_PP) * TPB + tid;
        slot = isPP ? 1 : 3;
        const float* yrow;
        float bias;
        int e0;
        if (isPP) {
            e0 = edges_pp[e];
            int e1 = edges_pp[NEDGE + e];
            yrow = p + e1 * DIM;
            bias = gamma_pp[e0] + gamma_pp[N_PP + e1];
        } else {
            e0 = edges_ap[e];
            int e1 = edges_ap[NEDGE + e];       // in [N_PP, N_PP+N_A)
            yrow = a + (e1 - N_PP) * DIM;
            bias = beta_ap[e0] + beta_ap[e1];
        }
        const float4* xp = (const float4*)(p_star + e0 * DIM);
        const float4* yp = (const float4*)yrow;
        float d2 = 0.f;
#pragma unroll
        for (int k = 0; k < 4; ++k) {
            float4 xv = xp[k], yv = yp[k];
            float dx = xv.x - yv.x, dy = xv.y - yv.y,
                  dz = xv.z - yv.z, dw = xv.w - yv.w;
            d2 += dx*dx + dy*dy + dz*dz + dw*dw;
        }
        val = bias - __builtin_amdgcn_sqrtf(d2);
    }

    float wsum = waveReduce(val);
    if ((tid & 63) == 0) smred[wid] = wsum;
    __syncthreads();
    if (tid == 0) {
        atomicAdd(&ws[slot], smred[0] + smred[1] + smred[2] + smred[3]);
        __threadfence();
        unsigned old = atomicAdd((unsigned*)(ws + 4), 1u);
        if (old == NB_TOTAL - 1) {
            // All other blocks' ws atomics happened-before their counter RMW.
            float s0 = atomicAdd(&ws[0], 0.f), s1 = atomicAdd(&ws[1], 0.f);
            float s2 = atomicAdd(&ws[2], 0.f), s3 = atomicAdd(&ws[3], 0.f);
            out[0] = 0.5f * (s0 - s1) / (float)N_PP
                   + 0.5f * (s2 - s3) / (float)N_A;
        }
    }
}

extern "C" void kernel_launch(void* const* d_in, const int* in_sizes, int n_in,
                              void* d_out, int out_size, void* d_ws, size_t ws_size,
                              hipStream_t stream) {
    const float* p_star   = (const float*)d_in[0];
    const float* p        = (const float*)d_in[1];
    const float* a        = (const float*)d_in[2];
    const float* beta_ap  = (const float*)d_in[3];
    const float* gamma_pp = (const float*)d_in[4];
    const int*   edges_pp = (const int*)d_in[5];
    const int*   edges_ap = (const int*)d_in[6];

    float* ws  = (float*)d_ws;
    float* out = (float*)d_out;

    hipLaunchKernelGGL(zero_ws_kernel, dim3(1), dim3(64), 0, stream, ws);
    hipLaunchKernelGGL(main_kernel, dim3(NB_TOTAL), dim3(TPB), 0, stream,
                       p_star, p, a, beta_ap, gamma_pp, edges_pp, edges_ap, ws, out);
}

// Round 4
// 233.262 us; speedup vs baseline: 1.0514x; 1.0514x over previous
//
#include <hip/hip_runtime.h>

#define N_PP   8192
#define N_A    8192
#define DIM    16
#define NEDGE  262144
#define TPB    256

// ---- ws float-unit layout (total ~1.02 MB) ----
// [0..3]=accums (nonlink_pp, link_pp, nonlink_ap, link_ap), [4]=counter.
// Data starts at float 64 (256 B) so accum atomics don't share cache lines.
#define WS_PSBF   64                    // p_star bf16-packed: 8192 rows x 8 u32
#define WS_PBF    (WS_PSBF + 65536)     // p packed
#define WS_ABF    (WS_PBF  + 65536)     // a packed
#define WS_X2PS   (WS_ABF  + 65536)     // |p_star|^2 fp32
#define WS_Y2P    (WS_X2PS + 8192)      // |p|^2
#define WS_Y2A    (WS_Y2P  + 8192)      // |a|^2
#define WS_EGR    (WS_Y2A  + 8192)      // exp(gamma_pp[i])        (pp row factor)
#define WS_EGC    (WS_EGR  + 8192)      // exp(gamma_pp[8192+j])   (pp col factor)
#define WS_EBR    (WS_EGC  + 8192)      // exp(beta_ap[i])         (ap row factor)
#define WS_EBC    (WS_EBR  + 8192)      // exp(beta_ap[8192+j])    (ap col factor)

// Block map: [0,2048) pp matrix (strips descending = longest-first),
// [2048,4096) ap matrix, [4096,4224) pp edges, [4224,4352) ap edges.
#define NB_TOTAL  4352

typedef short    bf16x8 __attribute__((ext_vector_type(8)));
typedef float    f32x4  __attribute__((ext_vector_type(4)));
typedef unsigned u32x4  __attribute__((ext_vector_type(4)));

__device__ __forceinline__ float waveReduce(float v) {
#pragma unroll
    for (int off = 32; off > 0; off >>= 1)
        v += __shfl_down(v, off, 64);
    return v;
}

// fp32 -> bf16 RNE, pure bit ops.
__device__ __forceinline__ unsigned bf16_rne(float f) {
    unsigned u = __builtin_bit_cast(unsigned, f);
    return (u + 0x7FFFu + ((u >> 16) & 1u)) >> 16;
}
__device__ __forceinline__ unsigned packbf2(float a, float b) {
    return bf16_rne(a) | (bf16_rne(b) << 16);
}

// 224 blocks x 256: rows [0,24576) convert points; [24576,57344) exp biases.
__global__ __launch_bounds__(TPB) void precompute_kernel(
    const float* __restrict__ p_star, const float* __restrict__ p,
    const float* __restrict__ a, const float* __restrict__ beta_ap,
    const float* __restrict__ gamma_pp, float* __restrict__ ws)
{
    const int g = blockIdx.x * TPB + threadIdx.x;
    if (g < 8) ws[g] = 0.0f;

    if (g < 3 * 8192) {
        const int arr = g >> 13, idx = g & 8191;
        const float* src = arr == 0 ? p_star : (arr == 1 ? p : a);
        const int bfo = arr == 0 ? WS_PSBF : (arr == 1 ? WS_PBF : WS_ABF);
        const int n2o = arr == 0 ? WS_X2PS : (arr == 1 ? WS_Y2P : WS_Y2A);
        const float4* rp = (const float4*)(src + idx * DIM);
        float4 f0 = rp[0], f1 = rp[1], f2 = rp[2], f3 = rp[3];
        float n2 = f0.x*f0.x + f0.y*f0.y + f0.z*f0.z + f0.w*f0.w
                 + f1.x*f1.x + f1.y*f1.y + f1.z*f1.z + f1.w*f1.w
                 + f2.x*f2.x + f2.y*f2.y + f2.z*f2.z + f2.w*f2.w
                 + f3.x*f3.x + f3.y*f3.y + f3.z*f3.z + f3.w*f3.w;
        u32x4 u0 = { packbf2(f0.x, f0.y), packbf2(f0.z, f0.w),
                     packbf2(f1.x, f1.y), packbf2(f1.z, f1.w) };
        u32x4 u1 = { packbf2(f2.x, f2.y), packbf2(f2.z, f2.w),
                     packbf2(f3.x, f3.y), packbf2(f3.z, f3.w) };
        u32x4* dst = (u32x4*)(ws + bfo) + idx * 2;
        dst[0] = u0; dst[1] = u1;
        ws[n2o + idx] = n2;
    } else {
        const int h = g - 3 * 8192;           // [0, 32768)
        const int q = h >> 13, i = h & 8191;
        float v;
        if      (q == 0) v = gamma_pp[i];
        else if (q == 1) v = gamma_pp[8192 + i];
        else if (q == 2) v = beta_ap[i];
        else             v = beta_ap[8192 + i];
        ws[WS_EGR + (q << 13) + i] = __expf(v);
    }
}

__global__ __launch_bounds__(TPB) void main_kernel(
    const float* __restrict__ p_star, const float* __restrict__ p,
    const float* __restrict__ a, const float* __restrict__ beta_ap,
    const float* __restrict__ gamma_pp, const int* __restrict__ edges_pp,
    const int* __restrict__ edges_ap, float* __restrict__ ws,
    float* __restrict__ out)
{
    __shared__ float smred[4];
    const int b = blockIdx.x, tid = threadIdx.x, wid = tid >> 6;
    const int lane = tid & 63, quad = lane >> 4, l16 = lane & 15;

    float val = 0.f;
    int slot;

    if (b < 4096) {
        // ---------- matrix part: wave = 16-col strip x interleaved 16-row tiles ----
        const bool isPP = (b < 2048);
        const int  bb   = isPP ? b : b - 2048;
        const int  strip = isPP ? (511 - (bb >> 2)) : (bb >> 2); // pp longest-first
        const int  w     = ((bb & 3) << 2) + wid;                // 0..15
        slot = isPP ? 0 : 2;

        const unsigned* Xbf = (const unsigned*)(ws + WS_PSBF);
        const unsigned* Ybf = (const unsigned*)(ws + (isPP ? WS_PBF : WS_ABF));
        const float* x2  = ws + WS_X2PS;
        const float* y2  = ws + (isPP ? WS_Y2P : WS_Y2A);
        const float* Er  = ws + (isPP ? WS_EGR : WS_EBR);
        const float* EcA = ws + (isPP ? WS_EGC : WS_EBC);

        const int jt = strip << 4;
        const int j  = jt + l16;

        bf16x8 bfrag = {};
        if (quad < 2)
            bfrag = __builtin_bit_cast(bf16x8, *(const u32x4*)(Ybf + j * 8 + quad * 4));
        const float y2c = y2[j];
        const float Ec  = EcA[j];

        const int tmax = isPP ? strip : 511;
        const f32x4 zero4 = {0.f, 0.f, 0.f, 0.f};
        float acc = 0.f;

        for (int t = w; t <= tmax; t += 16) {
            const int i0 = t << 4;
            bf16x8 afrag = {};
            if (quad < 2)
                afrag = __builtin_bit_cast(bf16x8,
                            *(const u32x4*)(Xbf + (i0 + l16) * 8 + quad * 4));
            const f32x4 er4 = *(const f32x4*)(Er + i0 + (quad << 2));
            const f32x4 x24 = *(const f32x4*)(x2 + i0 + (quad << 2));
            f32x4 d = __builtin_amdgcn_mfma_f32_16x16x32_bf16(afrag, bfrag, zero4, 0, 0, 0);
            const bool diag = isPP && (t == strip);
#pragma unroll
            for (int r = 0; r < 4; ++r) {
                float d2 = fmaf(-2.f, d[r], x24[r] + y2c);
                d2 = fmaxf(d2, 0.f);
                float ex = __expf(-__builtin_amdgcn_sqrtf(d2));
                float term = er4[r] * ex;
                if (diag && (j <= i0 + (quad << 2) + r)) term = 0.f;  // strict triu
                acc += term;
            }
        }
        val = acc * Ec;
    } else {
        // ---------- edge part: 128 blocks pp + 128 blocks ap, 8 edges/thread ----
        const int  eb   = b - 4096;
        const bool isPP = (eb < 128);
        const int  base = (isPP ? eb : eb - 128) * TPB + tid;   // 0..32767
        slot = isPP ? 1 : 3;
        float s = 0.f;
#pragma unroll
        for (int k = 0; k < 8; ++k) {
            const int e = base + k * 32768;
            const float* yrow;
            float bias;
            int e0;
            if (isPP) {
                e0 = edges_pp[e];
                int e1 = edges_pp[NEDGE + e];
                yrow = p + e1 * DIM;
                bias = gamma_pp[e0] + gamma_pp[N_PP + e1];
            } else {
                e0 = edges_ap[e];
                int e1 = edges_ap[NEDGE + e];
                yrow = a + (e1 - N_PP) * DIM;
                bias = beta_ap[e0] + beta_ap[e1];
            }
            const float4* xp = (const float4*)(p_star + e0 * DIM);
            const float4* yp = (const float4*)yrow;
            float d2 = 0.f;
#pragma unroll
            for (int kk = 0; kk < 4; ++kk) {
                float4 xv = xp[kk], yv = yp[kk];
                float dx = xv.x - yv.x, dy = xv.y - yv.y,
                      dz = xv.z - yv.z, dw = xv.w - yv.w;
                d2 += dx*dx + dy*dy + dz*dz + dw*dw;
            }
            s += bias - __builtin_amdgcn_sqrtf(d2);
        }
        val = s;
    }

    float wsum = waveReduce(val);
    if ((tid & 63) == 0) smred[wid] = wsum;
    __syncthreads();
    if (tid == 0) {
        atomicAdd(&ws[slot], smred[0] + smred[1] + smred[2] + smred[3]);
        __threadfence();
        unsigned old = atomicAdd((unsigned*)(ws + 4), 1u);
        if (old == NB_TOTAL - 1) {
            float s0 = atomicAdd(&ws[0], 0.f), s1 = atomicAdd(&ws[1], 0.f);
            float s2 = atomicAdd(&ws[2], 0.f), s3 = atomicAdd(&ws[3], 0.f);
            out[0] = 0.5f * (s0 - s1) / (float)N_PP
                   + 0.5f * (s2 - s3) / (float)N_A;
        }
    }
}

extern "C" void kernel_launch(void* const* d_in, const int* in_sizes, int n_in,
                              void* d_out, int out_size, void* d_ws, size_t ws_size,
                              hipStream_t stream) {
    const float* p_star   = (const float*)d_in[0];
    const float* p        = (const float*)d_in[1];
    const float* a        = (const float*)d_in[2];
    const float* beta_ap  = (const float*)d_in[3];
    const float* gamma_pp = (const float*)d_in[4];
    const int*   edges_pp = (const int*)d_in[5];
    const int*   edges_ap = (const int*)d_in[6];

    float* ws  = (float*)d_ws;
    float* out = (float*)d_out;

    hipLaunchKernelGGL(precompute_kernel, dim3(224), dim3(TPB), 0, stream,
                       p_star, p, a, beta_ap, gamma_pp, ws);
    hipLaunchKernelGGL(main_kernel, dim3(NB_TOTAL), dim3(TPB), 0, stream,
                       p_star, p, a, beta_ap, gamma_pp, edges_pp, edges_ap, ws, out);
}